// Round 3
// baseline (1547.211 us; speedup 1.0000x reference)
//
#include <hip/hip_runtime.h>

typedef unsigned short u16;
typedef unsigned int u32;
typedef __attribute__((ext_vector_type(8))) short short8;
typedef __attribute__((ext_vector_type(4))) float f32x4;
typedef __attribute__((ext_vector_type(4))) u16 u16x4;

#define AS1 __attribute__((address_space(1)))
#define AS3 __attribute__((address_space(3)))

// ---- constants ----
#define BB 5000
#define TT 8
#define VV 5264
#define HH 200
#define M1 40000        // B*T
#define K1 5264
#define K1P 5280        // 165*32
#define NKT 165
#define NT1 13          // 13*16 = 208 >= 200
#define N1PAD 224       // padded W_ih rows (zeros beyond 199)
#define K2P 224         // 7*32 padded H for fc
#define XHP_ELEMS 8000000ull  // 40000*200

__device__ __forceinline__ void gll16(const void* g, void* l) {
  __builtin_amdgcn_global_load_lds((AS1 void*)(void*)g, (AS3 void*)l, 16, 0, 0);
}

// split fp32 into bf16 hi (truncation) + bf16 lo (RNE of residual); x ~= hi + lo with ~2^-16 rel err
__device__ __forceinline__ void split1(float x, u16& hi, u16& lo) {
  u32 u = __builtin_bit_cast(u32, x);
  hi = (u16)(u >> 16);
  float hf = __builtin_bit_cast(float, u & 0xffff0000u);
  float r = x - hf;
  u32 ur = __builtin_bit_cast(u32, r);
  lo = (u16)((ur + 0x7fffu + ((ur >> 16) & 1u)) >> 16);
}

__device__ __forceinline__ float tanh_fast(float x) {
  float e = __expf(2.0f * x);
  return 1.0f - 2.0f / (e + 1.0f);
}

// ---------------- prep: split/pad weights ----------------
#define NE1 (224 * 5280)    // W_ih split, padded rows+K
#define NE2 (5264 * 224)    // W_fc split, padded K
#define NE3 (200 * 256)     // W_hh transposed, padded cols
__global__ void prep_kernel(const float* __restrict__ W_ih, const float* __restrict__ W_fc,
                            const float* __restrict__ W_hh,
                            u16* __restrict__ Whi, u16* __restrict__ Wlo,
                            u16* __restrict__ Fhi, u16* __restrict__ Flo,
                            float* __restrict__ WT) {
  int i = blockIdx.x * 256 + threadIdx.x;
  if (i < NE1) {
    int n = i / 5280, k = i - n * 5280;
    float v = (n < 200 && k < 5264) ? W_ih[(size_t)n * 5264 + k] : 0.0f;
    u16 h, l; split1(v, h, l);
    Whi[i] = h; Wlo[i] = l;
  } else if ((i -= NE1) < NE2) {
    int n = i / 224, k = i - n * 224;
    float v = (k < 200) ? W_fc[(size_t)n * 200 + k] : 0.0f;
    u16 h, l; split1(v, h, l);
    Fhi[i] = h; Flo[i] = l;
  } else if ((i -= NE2) < NE3) {
    int k = i >> 8, j = i & 255;
    WT[i] = (j < 200) ? W_hh[(size_t)j * 200 + k] : 0.0f;
  }
}

// ---------------- big GEMM: xh_partial[s] = X @ W_ih^T (split-bf16, 3-pass) ----------------
// grid = 313 * KS blocks, 256 threads. TM=128 (wave owns 2 row-tiles x all 13 col-tiles).
__global__ __launch_bounds__(256, 3) void g1_kernel(
    const float* __restrict__ X,
    const u16* __restrict__ Whi, const u16* __restrict__ Wlo,
    float* __restrict__ xhp, int KS) {
  __shared__ __align__(16) u16 lds[2][2][NT1][512];  // [buf][hi/lo][nt][lane*8] = 52 KB
  const int bid = blockIdx.x;
  const int s = bid % KS, mblk = bid / KS;
  const int kt0 = (NKT * s) / KS, kt1 = (NKT * (s + 1)) / KS;
  float* __restrict__ xout = xhp + (size_t)s * XHP_ELEMS;
  const int tid = threadIdx.x;
  const int w = tid >> 6, lane = tid & 63;
  const int l15 = lane & 15, g = lane >> 4;
  const int mbase = mblk * 128 + w * 32;
  const int mrow0 = mbase + l15, mrow1 = mrow0 + 16;

  f32x4 acc[2][NT1] = {};

  auto stage = [&](int buf, int kt) {
    // 26 (nt, half) jobs round-robin over 4 waves; dest fragment-ordered (lane-linear)
#pragma unroll
    for (int p0 = 0; p0 < 28; p0 += 4) {
      int p = w + p0;
      if (p < 26) {
        int nt = p >> 1, half = p & 1;
        const u16* srcb = half ? Wlo : Whi;
        const u16* src = srcb + (size_t)(nt * 16 + l15) * K1P + kt * 32 + g * 8;
        gll16(src, &lds[buf][half][nt][0]);
      }
    }
  };

  stage(0, kt0);
  int cur = 0;
  for (int kt = kt0; kt < kt1; ++kt) {
    __syncthreads();  // drains global_load_lds of buf[cur]; protects buf[cur^1] overwrite
    if (kt + 1 < kt1) stage(cur ^ 1, kt + 1);

    // A operand: fp32 direct from global, split in registers
    const int kb = kt * 32 + g * 8;
    const bool kok = kb < K1;
    short8 ah[2], al[2];
#pragma unroll
    for (int mt = 0; mt < 2; ++mt) {
      const int m = mt ? mrow1 : mrow0;
      f32x4 v0 = {0.f, 0.f, 0.f, 0.f}, v1 = {0.f, 0.f, 0.f, 0.f};
      if (kok && m < M1) {
        const f32x4* xp = (const f32x4*)(X + (size_t)m * K1 + kb);
        v0 = xp[0]; v1 = xp[1];
      }
#pragma unroll
      for (int j = 0; j < 4; ++j) {
        u16 h, l;
        split1(v0[j], h, l); ah[mt][j] = (short)h; al[mt][j] = (short)l;
      }
#pragma unroll
      for (int j = 0; j < 4; ++j) {
        u16 h, l;
        split1(v1[j], h, l); ah[mt][4 + j] = (short)h; al[mt][4 + j] = (short)l;
      }
    }

#pragma unroll
    for (int nt = 0; nt < NT1; ++nt) {
      short8 bh = *(const short8*)&lds[cur][0][nt][lane * 8];
      short8 bl = *(const short8*)&lds[cur][1][nt][lane * 8];
#pragma unroll
      for (int mt = 0; mt < 2; ++mt) {
        acc[mt][nt] = __builtin_amdgcn_mfma_f32_16x16x32_bf16(ah[mt], bh, acc[mt][nt], 0, 0, 0);
        acc[mt][nt] = __builtin_amdgcn_mfma_f32_16x16x32_bf16(al[mt], bh, acc[mt][nt], 0, 0, 0);
        acc[mt][nt] = __builtin_amdgcn_mfma_f32_16x16x32_bf16(ah[mt], bl, acc[mt][nt], 0, 0, 0);
      }
    }
    cur ^= 1;
  }

  // epilogue: C/D layout col = lane&15, row = (lane>>4)*4 + r
#pragma unroll
  for (int mt = 0; mt < 2; ++mt) {
    const int rowb = mbase + mt * 16 + g * 4;
#pragma unroll
    for (int nt = 0; nt < NT1; ++nt) {
      const int col = nt * 16 + l15;
      if (col < HH) {
#pragma unroll
        for (int r = 0; r < 4; ++r) {
          const int m = rowb + r;
          if (m < M1) xout[(size_t)m * HH + col] = acc[mt][nt][r];
        }
      }
    }
  }
}

// ---------------- scan: h_t = tanh(xh_t + bias + h_{t-1} @ W_hh^T), fused 8 steps ----------------
// 625 blocks x 256 threads; block owns 8 batch rows; thread (jt,bt): 4 j-cols x 2 b-rows.
__global__ void scan_kernel(
    const float* __restrict__ xhp, int KS,
    const float* __restrict__ h0,
    const float* __restrict__ WT,      // [200][256] = W_hh^T, cols >=200 zero
    const float* __restrict__ b_ih, const float* __restrict__ b_hh,
    u16* __restrict__ Hhi, u16* __restrict__ Hlo) {
  __shared__ __align__(16) float hlds[8][200];
  const int tid = threadIdx.x;
  const int jt = tid & 63, bt = tid >> 6;
  const int b0 = bt * 2, b1 = b0 + 1;
  const int brow = blockIdx.x * 8;

  for (int i = tid; i < 8 * HH; i += 256) hlds[i / HH][i % HH] = h0[(size_t)brow * HH + i];

  f32x4 bias = {0.f, 0.f, 0.f, 0.f};
  if (jt < 50) bias = *(const f32x4*)(b_ih + jt * 4) + *(const f32x4*)(b_hh + jt * 4);
  __syncthreads();

  f32x4 hc0 = {0.f, 0.f, 0.f, 0.f}, hc1 = {0.f, 0.f, 0.f, 0.f};
  for (int t = 0; t < TT; ++t) {
    f32x4 a0 = {0.f, 0.f, 0.f, 0.f}, a1 = {0.f, 0.f, 0.f, 0.f};
    for (int kq = 0; kq < 50; ++kq) {
      f32x4 hv0 = *(const f32x4*)&hlds[b0][kq * 4];
      f32x4 hv1 = *(const f32x4*)&hlds[b1][kq * 4];
#pragma unroll
      for (int kk = 0; kk < 4; ++kk) {
        f32x4 wv = *(const f32x4*)(WT + (size_t)(kq * 4 + kk) * 256 + jt * 4);
        a0 += hv0[kk] * wv;
        a1 += hv1[kk] * wv;
      }
    }
    if (jt < 50) {
      size_t m0 = ((size_t)(brow + b0) * TT + t) * HH + jt * 4;
      size_t m1 = ((size_t)(brow + b1) * TT + t) * HH + jt * 4;
      f32x4 x0 = bias + a0, x1 = bias + a1;
      for (int ss = 0; ss < KS; ++ss) {
        x0 += *(const f32x4*)(xhp + (size_t)ss * XHP_ELEMS + m0);
        x1 += *(const f32x4*)(xhp + (size_t)ss * XHP_ELEMS + m1);
      }
#pragma unroll
      for (int c = 0; c < 4; ++c) { hc0[c] = tanh_fast(x0[c]); hc1[c] = tanh_fast(x1[c]); }
    }
    __syncthreads();
    if (jt < 50) {
      *(f32x4*)&hlds[b0][jt * 4] = hc0;
      *(f32x4*)&hlds[b1][jt * 4] = hc1;
    }
    __syncthreads();
  }

  // write h_last split to bf16, K padded to 224 with zeros (jt 50..55 have hc==0)
  if (jt < 56) {
    u16x4 h0v, l0v, h1v, l1v;
#pragma unroll
    for (int c = 0; c < 4; ++c) {
      u16 hh, ll;
      split1(hc0[c], hh, ll); h0v[c] = hh; l0v[c] = ll;
      split1(hc1[c], hh, ll); h1v[c] = hh; l1v[c] = ll;
    }
    size_t o0 = (size_t)(brow + b0) * K2P + jt * 4;
    size_t o1 = (size_t)(brow + b1) * K2P + jt * 4;
    *(u16x4*)(Hhi + o0) = h0v; *(u16x4*)(Hlo + o0) = l0v;
    *(u16x4*)(Hhi + o1) = h1v; *(u16x4*)(Hlo + o1) = l1v;
  }
}

// ---------------- fc: out = h_last @ W_fc^T + b_fc (split-bf16, 3-pass) ----------------
// grid 40x42 (flattened), 128x128 tile, wave = 64x64.
__global__ __launch_bounds__(256, 3) void fc_kernel(
    const u16* __restrict__ Ahi, const u16* __restrict__ Alo,
    const u16* __restrict__ Bhi, const u16* __restrict__ Blo,
    const float* __restrict__ bfc, float* __restrict__ out) {
  __shared__ __align__(16) u16 lds[2][2][8][512];  // [A/B][hi/lo][tile][lane*8] = 32 KB
  const int bid = blockIdx.x;
  const int mb = bid / 42, nb = bid % 42;
  const int tid = threadIdx.x, w = tid >> 6, lane = tid & 63;
  const int wm = w >> 1, wn = w & 1;
  const int l15 = lane & 15, g = lane >> 4;
  f32x4 acc[4][4] = {};

  for (int kt = 0; kt < 7; ++kt) {
#pragma unroll
    for (int p0 = 0; p0 < 32; p0 += 4) {
      int p = w + p0;
      int side = p >> 4, half = (p >> 3) & 1, tile = p & 7;
      const u16* src;
      if (side == 0) {
        int m = mb * 128 + tile * 16 + l15; if (m > BB - 1) m = BB - 1;
        src = (half ? Alo : Ahi) + (size_t)m * K2P;
      } else {
        int n = nb * 128 + tile * 16 + l15; if (n > VV - 1) n = VV - 1;
        src = (half ? Blo : Bhi) + (size_t)n * K2P;
      }
      src += kt * 32 + g * 8;
      gll16(src, &lds[side][half][tile][0]);
    }
    __syncthreads();

    short8 af[4][2];
#pragma unroll
    for (int mt = 0; mt < 4; ++mt) {
      af[mt][0] = *(const short8*)&lds[0][0][wm * 4 + mt][lane * 8];
      af[mt][1] = *(const short8*)&lds[0][1][wm * 4 + mt][lane * 8];
    }
#pragma unroll
    for (int nt = 0; nt < 4; ++nt) {
      short8 bh = *(const short8*)&lds[1][0][wn * 4 + nt][lane * 8];
      short8 bl = *(const short8*)&lds[1][1][wn * 4 + nt][lane * 8];
#pragma unroll
      for (int mt = 0; mt < 4; ++mt) {
        acc[mt][nt] = __builtin_amdgcn_mfma_f32_16x16x32_bf16(af[mt][0], bh, acc[mt][nt], 0, 0, 0);
        acc[mt][nt] = __builtin_amdgcn_mfma_f32_16x16x32_bf16(af[mt][1], bh, acc[mt][nt], 0, 0, 0);
        acc[mt][nt] = __builtin_amdgcn_mfma_f32_16x16x32_bf16(af[mt][0], bl, acc[mt][nt], 0, 0, 0);
      }
    }
    __syncthreads();
  }

#pragma unroll
  for (int nt = 0; nt < 4; ++nt) {
    const int col = nb * 128 + wn * 64 + nt * 16 + l15;
    if (col < VV) {
      const float bv = bfc[col];
#pragma unroll
      for (int mt = 0; mt < 4; ++mt) {
        const int rowb = mb * 128 + wm * 64 + mt * 16 + g * 4;
#pragma unroll
        for (int r = 0; r < 4; ++r) {
          const int row = rowb + r;
          if (row < BB) out[(size_t)row * VV + col] = acc[mt][nt][r] + bv;
        }
      }
    }
  }
}

extern "C" void kernel_launch(void* const* d_in, const int* in_sizes, int n_in,
                              void* d_out, int out_size, void* d_ws, size_t ws_size,
                              hipStream_t stream) {
  (void)in_sizes; (void)n_in; (void)out_size;
  const float* X    = (const float*)d_in[0];
  const float* h0   = (const float*)d_in[1];
  const float* W_ih = (const float*)d_in[2];
  const float* W_hh = (const float*)d_in[3];
  const float* b_ih = (const float*)d_in[4];
  const float* b_hh = (const float*)d_in[5];
  const float* W_fc = (const float*)d_in[6];
  const float* b_fc = (const float*)d_in[7];
  float* out = (float*)d_out;

  char* ws = (char*)d_ws;
  size_t off = 0;
  auto alloc = [&](size_t bytes) -> void* {
    void* p = ws + off;
    off += (bytes + 255) & ~(size_t)255;
    return p;
  };
  u16* Whi = (u16*)alloc((size_t)N1PAD * K1P * 2);
  u16* Wlo = (u16*)alloc((size_t)N1PAD * K1P * 2);
  u16* Fhi = (u16*)alloc((size_t)VV * K2P * 2);
  u16* Flo = (u16*)alloc((size_t)VV * K2P * 2);
  float* WT = (float*)alloc((size_t)200 * 256 * 4);
  u16* Hhi = (u16*)alloc((size_t)BB * K2P * 2);
  u16* Hlo = (u16*)alloc((size_t)BB * K2P * 2);
  size_t fixed = off;

  int KS = 1;
  if (ws_size >= fixed + 4ull * XHP_ELEMS * 4ull) KS = 4;
  else if (ws_size >= fixed + 2ull * XHP_ELEMS * 4ull) KS = 2;
  float* xhp = (float*)alloc((size_t)KS * XHP_ELEMS * 4ull);

  const int prep_total = NE1 + NE2 + NE3;
  prep_kernel<<<(prep_total + 255) / 256, 256, 0, stream>>>(W_ih, W_fc, W_hh, Whi, Wlo, Fhi, Flo, WT);
  g1_kernel<<<313 * KS, 256, 0, stream>>>(X, Whi, Wlo, xhp, KS);
  scan_kernel<<<625, 256, 0, stream>>>(xhp, KS, h0, WT, b_ih, b_hh, Hhi, Hlo);
  fc_kernel<<<40 * 42, 256, 0, stream>>>(Hhi, Hlo, Fhi, Flo, b_fc, out);
}